// Round 1
// baseline (4721.891 us; speedup 1.0000x reference)
//
#include <hip/hip_runtime.h>
#include <math.h>

#define KS 5
#define K3 125

// ---------- helpers ----------

__device__ __forceinline__ unsigned encf(float f) {
    unsigned u = __float_as_uint(f);
    return (u & 0x80000000u) ? ~u : (u | 0x80000000u);
}
__device__ __forceinline__ float decf(unsigned e) {
    unsigned u = (e & 0x80000000u) ? (e ^ 0x80000000u) : ~e;
    return __uint_as_float(u);
}

__device__ __forceinline__ void spline_basis(const float ps[3], float w[8], int flat[8]) {
    float f[3]; int k0[3];
    #pragma unroll
    for (int d = 0; d < 3; d++) {
        float v = ps[d] * (float)(KS - 1);
        float kf = floorf(v);
        kf = fminf(fmaxf(kf, 0.0f), (float)(KS - 2));
        k0[d] = (int)kf;
        f[d] = v - kf;
    }
    #pragma unroll
    for (int c = 0; c < 8; c++) {
        float wc = 1.0f; int id[3];
        #pragma unroll
        for (int d = 0; d < 3; d++) {
            int b = (c >> d) & 1;
            wc *= b ? f[d] : (1.0f - f[d]);
            id[d] = k0[d] + b;
        }
        w[c] = wc;
        flat[c] = (id[0] * KS + id[1]) * KS + id[2];
    }
}

// ---------- pooling ----------

__global__ void pool_enc_kernel(const float* __restrict__ in, const int* __restrict__ cluster,
                                unsigned* __restrict__ enc, int n_in, int C) {
    int tid = blockIdx.x * blockDim.x + threadIdx.x;
    if (tid >= n_in * C) return;
    int node = tid / C, c = tid - node * C;
    atomicMax(&enc[(size_t)cluster[node] * C + c], encf(in[tid]));
}

__global__ void decode_kernel(const unsigned* __restrict__ enc, float* __restrict__ out, int n) {
    int tid = blockIdx.x * blockDim.x + threadIdx.x;
    if (tid >= n) return;
    unsigned e = enc[tid];
    out[tid] = (e == 0u) ? 0.0f : decf(e);
}

// ---------- spline conv, level 1 (cin = 1, cout = 32): thread per edge ----------

__global__ void conv1_kernel(const float* __restrict__ x, const int* __restrict__ ei,
                             const float* __restrict__ pseudo, const float* __restrict__ W,
                             float* __restrict__ agg, float* __restrict__ deg, int E) {
    int e = blockIdx.x * blockDim.x + threadIdx.x;
    if (e >= E) return;
    int src = ei[e], dst = ei[E + e];
    float ps[3] = {pseudo[e * 3], pseudo[e * 3 + 1], pseudo[e * 3 + 2]};
    float w[8]; int flat[8];
    spline_basis(ps, w, flat);
    float xv = x[src];
    float acc[32];
    #pragma unroll
    for (int o = 0; o < 32; o++) acc[o] = 0.0f;
    #pragma unroll
    for (int c = 0; c < 8; c++) {
        const float* Wk = W + flat[c] * 32;   // [K3,1,32]
        float wc = w[c];
        #pragma unroll
        for (int o = 0; o < 32; o++) acc[o] += wc * Wk[o];
    }
    float* ag = agg + (size_t)dst * 32;
    #pragma unroll
    for (int o = 0; o < 32; o++) atomicAdd(&ag[o], acc[o] * xv);
    atomicAdd(&deg[dst], 1.0f);
}

// ---------- spline conv, levels 2/3 (cin = cout = 32): 32 threads per edge ----------

__global__ void conv32_kernel(const float* __restrict__ x, const int* __restrict__ ei,
                              const float* __restrict__ pseudo, const float* __restrict__ W,
                              float* __restrict__ agg, float* __restrict__ deg, int E) {
    int tid = blockIdx.x * blockDim.x + threadIdx.x;
    int e = tid >> 5, o = tid & 31;
    if (e >= E) return;
    int src = ei[e], dst = ei[E + e];
    float ps[3] = {pseudo[e * 3], pseudo[e * 3 + 1], pseudo[e * 3 + 2]};
    float w[8]; int flat[8];
    spline_basis(ps, w, flat);
    const float* xj = x + (size_t)src * 32;
    float acc = 0.0f;
    #pragma unroll
    for (int c = 0; c < 8; c++) {
        const float* Wk = W + flat[c] * 1024 + o;  // [K3,32,32]
        float s = 0.0f;
        #pragma unroll
        for (int i = 0; i < 32; i++) s += xj[i] * Wk[i * 32];
        acc += w[c] * s;
    }
    atomicAdd(&agg[(size_t)dst * 32 + o], acc);
    if (o == 0) atomicAdd(&deg[dst], 1.0f);
}

// ---------- finalize: mean-normalize + root + bias + ELU ----------

__global__ void finalize1_kernel(const float* __restrict__ agg, const float* __restrict__ deg,
                                 const float* __restrict__ x, const float* __restrict__ root,
                                 const float* __restrict__ b, float* __restrict__ out, int n) {
    int tid = blockIdx.x * blockDim.x + threadIdx.x;
    if (tid >= n * 32) return;
    int nd = tid >> 5, o = tid & 31;
    float v = agg[tid] / fmaxf(deg[nd], 1.0f) + x[nd] * root[o] + b[o];
    out[tid] = (v > 0.0f) ? v : expm1f(v);
}

__global__ void finalize32_kernel(const float* __restrict__ agg, const float* __restrict__ deg,
                                  const float* __restrict__ x, const float* __restrict__ root,
                                  const float* __restrict__ b, float* __restrict__ out, int n) {
    int tid = blockIdx.x * blockDim.x + threadIdx.x;
    if (tid >= n * 32) return;
    int nd = tid >> 5, o = tid & 31;
    float v = agg[tid] / fmaxf(deg[nd], 1.0f);
    const float* xr = x + (size_t)nd * 32;
    float r = 0.0f;
    #pragma unroll
    for (int i = 0; i < 32; i++) r += xr[i] * root[i * 32 + o];
    v += r + b[o];
    out[tid] = (v > 0.0f) ? v : expm1f(v);
}

// ---------- FC + log_softmax: one thread per batch row ----------

__global__ void fc_kernel(const float* __restrict__ h, const float* __restrict__ fw,
                          const float* __restrict__ fb, float* __restrict__ out, int B) {
    int b = blockIdx.x * blockDim.x + threadIdx.x;
    if (b >= B) return;
    float logit[10];
    #pragma unroll
    for (int j = 0; j < 10; j++) logit[j] = fb[j];
    const float* hb = h + (size_t)b * 256;
    for (int t = 0; t < 256; t++) {
        float hv = hb[t];
        const float* fwt = fw + t * 10;
        #pragma unroll
        for (int j = 0; j < 10; j++) logit[j] += hv * fwt[j];
    }
    float m = logit[0];
    #pragma unroll
    for (int j = 1; j < 10; j++) m = fmaxf(m, logit[j]);
    float s = 0.0f;
    #pragma unroll
    for (int j = 0; j < 10; j++) s += expf(logit[j] - m);
    float lse = logf(s) + m;
    #pragma unroll
    for (int j = 0; j < 10; j++) out[(size_t)b * 10 + j] = logit[j] - lse;
}

// ---------- launch ----------

static inline int cdiv(long long a, int b) { return (int)((a + b - 1) / b); }

extern "C" void kernel_launch(void* const* d_in, const int* in_sizes, int n_in,
                              void* d_out, int out_size, void* d_ws, size_t ws_size,
                              hipStream_t stream) {
    const int N0 = 131072, N1 = 65536, N2 = 32768, N3 = 16384, B8 = 16384;
    const int B = B8 / 8;

    const float* x      = (const float*)d_in[0];
    const int*   cl0    = (const int*)d_in[1];
    const int*   ei1    = (const int*)d_in[2];
    const float* ps1    = (const float*)d_in[3];
    const int*   cl1    = (const int*)d_in[4];
    const int*   ei2    = (const int*)d_in[5];
    const float* ps2    = (const float*)d_in[6];
    const int*   cl2    = (const int*)d_in[7];
    const int*   ei3    = (const int*)d_in[8];
    const float* ps3    = (const float*)d_in[9];
    const int*   cl3    = (const int*)d_in[10];
    const float* W1     = (const float*)d_in[11];
    const float* root1  = (const float*)d_in[12];
    const float* b1     = (const float*)d_in[13];
    const float* W2     = (const float*)d_in[14];
    const float* root2  = (const float*)d_in[15];
    const float* b2     = (const float*)d_in[16];
    const float* W3     = (const float*)d_in[17];
    const float* root3  = (const float*)d_in[18];
    const float* b3     = (const float*)d_in[19];
    const float* fc_w   = (const float*)d_in[20];
    const float* fc_b   = (const float*)d_in[21];
    float* out = (float*)d_out;

    const int E1 = in_sizes[2] / 2;
    const int E2 = in_sizes[5] / 2;
    const int E3 = in_sizes[8] / 2;

    // workspace layout (floats)
    float* ws  = (float*)d_ws;
    float* p0  = ws;                 // N1
    float* h1  = p0 + N1;            // N1*32
    float* p1  = h1 + (size_t)N1*32; // N2*32
    float* h2  = p1 + (size_t)N2*32; // N2*32
    float* p2  = h2 + (size_t)N2*32; // N3*32
    float* h3  = p2 + (size_t)N3*32; // N3*32
    float* p3  = h3 + (size_t)N3*32; // B8*32
    float* acc = p3 + (size_t)B8*32; // N1*32 (reused across levels)
    float* deg = acc + (size_t)N1*32;// N1 (reused)
    unsigned* enc = (unsigned*)(deg + N1); // max N2*32 (reused)

    const int T = 256;

    // ---- level 0 pool: x [N0,1] -> p0 [N1] ----
    hipMemsetAsync(enc, 0, (size_t)N1 * 4, stream);
    pool_enc_kernel<<<cdiv(N0, T), T, 0, stream>>>(x, cl0, enc, N0, 1);
    decode_kernel<<<cdiv(N1, T), T, 0, stream>>>(enc, p0, N1);

    // ---- conv1: p0 -> h1 [N1,32] ----
    hipMemsetAsync(acc, 0, (size_t)N1 * 32 * 4, stream);
    hipMemsetAsync(deg, 0, (size_t)N1 * 4, stream);
    conv1_kernel<<<cdiv(E1, T), T, 0, stream>>>(p0, ei1, ps1, W1, acc, deg, E1);
    finalize1_kernel<<<cdiv((long long)N1 * 32, T), T, 0, stream>>>(acc, deg, p0, root1, b1, h1, N1);

    // ---- pool1: h1 [N1,32] -> p1 [N2,32] ----
    hipMemsetAsync(enc, 0, (size_t)N2 * 32 * 4, stream);
    pool_enc_kernel<<<cdiv((long long)N1 * 32, T), T, 0, stream>>>(h1, cl1, enc, N1, 32);
    decode_kernel<<<cdiv((long long)N2 * 32, T), T, 0, stream>>>(enc, p1, N2 * 32);

    // ---- conv2: p1 -> h2 [N2,32] ----
    hipMemsetAsync(acc, 0, (size_t)N2 * 32 * 4, stream);
    hipMemsetAsync(deg, 0, (size_t)N2 * 4, stream);
    conv32_kernel<<<cdiv((long long)E2 * 32, T), T, 0, stream>>>(p1, ei2, ps2, W2, acc, deg, E2);
    finalize32_kernel<<<cdiv((long long)N2 * 32, T), T, 0, stream>>>(acc, deg, p1, root2, b2, h2, N2);

    // ---- pool2: h2 [N2,32] -> p2 [N3,32] ----
    hipMemsetAsync(enc, 0, (size_t)N3 * 32 * 4, stream);
    pool_enc_kernel<<<cdiv((long long)N2 * 32, T), T, 0, stream>>>(h2, cl2, enc, N2, 32);
    decode_kernel<<<cdiv((long long)N3 * 32, T), T, 0, stream>>>(enc, p2, N3 * 32);

    // ---- conv3: p2 -> h3 [N3,32] ----
    hipMemsetAsync(acc, 0, (size_t)N3 * 32 * 4, stream);
    hipMemsetAsync(deg, 0, (size_t)N3 * 4, stream);
    conv32_kernel<<<cdiv((long long)E3 * 32, T), T, 0, stream>>>(p2, ei3, ps3, W3, acc, deg, E3);
    finalize32_kernel<<<cdiv((long long)N3 * 32, T), T, 0, stream>>>(acc, deg, p2, root3, b3, h3, N3);

    // ---- pool3: h3 [N3,32] -> p3 [B8,32] ----
    hipMemsetAsync(enc, 0, (size_t)B8 * 32 * 4, stream);
    pool_enc_kernel<<<cdiv((long long)N3 * 32, T), T, 0, stream>>>(h3, cl3, enc, N3, 32);
    decode_kernel<<<cdiv((long long)B8 * 32, T), T, 0, stream>>>(enc, p3, B8 * 32);

    // ---- FC + log_softmax: p3 viewed as [B,256] -> out [B,10] ----
    fc_kernel<<<cdiv(B, T), T, 0, stream>>>(p3, fc_w, fc_b, out, B);
}

// Round 2
// 3163.760 us; speedup vs baseline: 1.4925x; 1.4925x over previous
//
#include <hip/hip_runtime.h>
#include <math.h>

#define KS 5
#define K3 125

// ---------- helpers ----------

__device__ __forceinline__ unsigned encf(float f) {
    unsigned u = __float_as_uint(f);
    return (u & 0x80000000u) ? ~u : (u | 0x80000000u);
}
__device__ __forceinline__ float decf(unsigned e) {
    unsigned u = (e & 0x80000000u) ? (e ^ 0x80000000u) : ~e;
    return __uint_as_float(u);
}

__device__ __forceinline__ void spline_basis(const float ps[3], float w[8], int flat[8]) {
    float f[3]; int k0[3];
    #pragma unroll
    for (int d = 0; d < 3; d++) {
        float v = ps[d] * (float)(KS - 1);
        float kf = floorf(v);
        kf = fminf(fmaxf(kf, 0.0f), (float)(KS - 2));
        k0[d] = (int)kf;
        f[d] = v - kf;
    }
    #pragma unroll
    for (int c = 0; c < 8; c++) {
        float wc = 1.0f; int id[3];
        #pragma unroll
        for (int d = 0; d < 3; d++) {
            int b = (c >> d) & 1;
            wc *= b ? f[d] : (1.0f - f[d]);
            id[d] = k0[d] + b;
        }
        w[c] = wc;
        flat[c] = (id[0] * KS + id[1]) * KS + id[2];
    }
}

// ---------- pooling ----------

__global__ void pool_enc_kernel(const float* __restrict__ in, const int* __restrict__ cluster,
                                unsigned* __restrict__ enc, int n_in, int C) {
    int tid = blockIdx.x * blockDim.x + threadIdx.x;
    if (tid >= n_in * C) return;
    int node = tid / C, c = tid - node * C;
    atomicMax(&enc[(size_t)cluster[node] * C + c], encf(in[tid]));
}

__global__ void decode_kernel(const unsigned* __restrict__ enc, float* __restrict__ out, int n) {
    int tid = blockIdx.x * blockDim.x + threadIdx.x;
    if (tid >= n) return;
    unsigned e = enc[tid];
    out[tid] = (e == 0u) ? 0.0f : decf(e);
}

// ---------- CSR construction (edges grouped by dst) ----------

__global__ void hist_kernel(const int* __restrict__ ei, int* __restrict__ cnt, int E) {
    int e = blockIdx.x * blockDim.x + threadIdx.x;
    if (e >= E) return;
    atomicAdd(&cnt[ei[E + e]], 1);
}

// single-block exclusive scan: cnt[0..n) -> row_start[0..n], row_start[n]=total
__global__ void scan_kernel(const int* __restrict__ cnt, int* __restrict__ row_start, int n) {
    __shared__ int sdata[1024];
    __shared__ int carry;
    int t = threadIdx.x;
    if (t == 0) carry = 0;
    __syncthreads();
    for (int base = 0; base < n; base += 1024) {
        int i = base + t;
        int v = (i < n) ? cnt[i] : 0;
        sdata[t] = v;
        __syncthreads();
        for (int off = 1; off < 1024; off <<= 1) {
            int add = (t >= off) ? sdata[t - off] : 0;
            __syncthreads();
            sdata[t] += add;
            __syncthreads();
        }
        int incl = sdata[t];
        int total = sdata[1023];
        if (i < n) row_start[i] = carry + incl - v;
        __syncthreads();
        if (t == 0) carry += total;
        __syncthreads();
    }
    if (t == 0) row_start[n] = carry;
}

__global__ void scatter_kernel(const int* __restrict__ ei, int* __restrict__ cursor,
                               const int* __restrict__ row_start, int* __restrict__ csr, int E) {
    int e = blockIdx.x * blockDim.x + threadIdx.x;
    if (e >= E) return;
    int dst = ei[E + e];
    int pos = atomicAdd(&cursor[dst], 1);
    csr[row_start[dst] + pos] = e;
}

// ---------- node-centric spline conv, fused finalize (no atomics) ----------

// level 1: cin = 1, cout = 32. 32 threads per node.
__global__ void conv1_node_kernel(const float* __restrict__ x, const int* __restrict__ ei,
                                  const float* __restrict__ pseudo,
                                  const int* __restrict__ row_start, const int* __restrict__ csr,
                                  const float* __restrict__ W, const float* __restrict__ root,
                                  const float* __restrict__ b, float* __restrict__ out, int n) {
    int tid = blockIdx.x * blockDim.x + threadIdx.x;
    int nd = tid >> 5, o = tid & 31;
    if (nd >= n) return;
    int beg = row_start[nd], end = row_start[nd + 1];
    float acc = 0.0f;
    for (int idx = beg; idx < end; idx++) {
        int e = csr[idx];
        int src = ei[e];
        float ps[3] = {pseudo[e * 3], pseudo[e * 3 + 1], pseudo[e * 3 + 2]};
        float w[8]; int flat[8];
        spline_basis(ps, w, flat);
        float s = 0.0f;
        #pragma unroll
        for (int c = 0; c < 8; c++) s += w[c] * W[flat[c] * 32 + o];
        acc += s * x[src];
    }
    float v = acc / fmaxf((float)(end - beg), 1.0f) + x[nd] * root[o] + b[o];
    out[(size_t)nd * 32 + o] = (v > 0.0f) ? v : expm1f(v);
}

// levels 2/3: cin = cout = 32. 32 threads per node, thread o owns output channel o.
__global__ void conv32_node_kernel(const float* __restrict__ x, const int* __restrict__ ei,
                                   const float* __restrict__ pseudo,
                                   const int* __restrict__ row_start, const int* __restrict__ csr,
                                   const float* __restrict__ W, const float* __restrict__ root,
                                   const float* __restrict__ b, float* __restrict__ out, int n) {
    int tid = blockIdx.x * blockDim.x + threadIdx.x;
    int nd = tid >> 5, o = tid & 31;
    if (nd >= n) return;
    int beg = row_start[nd], end = row_start[nd + 1];
    float acc = 0.0f;
    for (int idx = beg; idx < end; idx++) {
        int e = csr[idx];
        int src = ei[e];
        float ps[3] = {pseudo[e * 3], pseudo[e * 3 + 1], pseudo[e * 3 + 2]};
        float w[8]; int flat[8];
        spline_basis(ps, w, flat);
        const float* __restrict__ xj = x + (size_t)src * 32;
        float xv[32];
        #pragma unroll
        for (int i = 0; i < 32; i++) xv[i] = xj[i];
        #pragma unroll
        for (int c = 0; c < 8; c++) {
            const float* __restrict__ Wk = W + flat[c] * 1024 + o;
            float s = 0.0f;
            #pragma unroll
            for (int i = 0; i < 32; i++) s += xv[i] * Wk[i * 32];
            acc += w[c] * s;
        }
    }
    acc /= fmaxf((float)(end - beg), 1.0f);
    const float* __restrict__ xr = x + (size_t)nd * 32;
    float r = 0.0f;
    #pragma unroll
    for (int i = 0; i < 32; i++) r += xr[i] * root[i * 32 + o];
    float v = acc + r + b[o];
    out[(size_t)nd * 32 + o] = (v > 0.0f) ? v : expm1f(v);
}

// ---------- FC + log_softmax: one thread per batch row ----------

__global__ void fc_kernel(const float* __restrict__ h, const float* __restrict__ fw,
                          const float* __restrict__ fb, float* __restrict__ out, int B) {
    int b = blockIdx.x * blockDim.x + threadIdx.x;
    if (b >= B) return;
    float logit[10];
    #pragma unroll
    for (int j = 0; j < 10; j++) logit[j] = fb[j];
    const float* hb = h + (size_t)b * 256;
    for (int t = 0; t < 256; t++) {
        float hv = hb[t];
        const float* fwt = fw + t * 10;
        #pragma unroll
        for (int j = 0; j < 10; j++) logit[j] += hv * fwt[j];
    }
    float m = logit[0];
    #pragma unroll
    for (int j = 1; j < 10; j++) m = fmaxf(m, logit[j]);
    float s = 0.0f;
    #pragma unroll
    for (int j = 0; j < 10; j++) s += expf(logit[j] - m);
    float lse = logf(s) + m;
    #pragma unroll
    for (int j = 0; j < 10; j++) out[(size_t)b * 10 + j] = logit[j] - lse;
}

// ---------- launch ----------

static inline int cdiv(long long a, int b) { return (int)((a + b - 1) / b); }

extern "C" void kernel_launch(void* const* d_in, const int* in_sizes, int n_in,
                              void* d_out, int out_size, void* d_ws, size_t ws_size,
                              hipStream_t stream) {
    const int N0 = 131072, N1 = 65536, N2 = 32768, N3 = 16384, B8 = 16384;
    const int B = B8 / 8;

    const float* x      = (const float*)d_in[0];
    const int*   cl0    = (const int*)d_in[1];
    const int*   ei1    = (const int*)d_in[2];
    const float* ps1    = (const float*)d_in[3];
    const int*   cl1    = (const int*)d_in[4];
    const int*   ei2    = (const int*)d_in[5];
    const float* ps2    = (const float*)d_in[6];
    const int*   cl2    = (const int*)d_in[7];
    const int*   ei3    = (const int*)d_in[8];
    const float* ps3    = (const float*)d_in[9];
    const int*   cl3    = (const int*)d_in[10];
    const float* W1     = (const float*)d_in[11];
    const float* root1  = (const float*)d_in[12];
    const float* b1     = (const float*)d_in[13];
    const float* W2     = (const float*)d_in[14];
    const float* root2  = (const float*)d_in[15];
    const float* b2     = (const float*)d_in[16];
    const float* W3     = (const float*)d_in[17];
    const float* root3  = (const float*)d_in[18];
    const float* b3     = (const float*)d_in[19];
    const float* fc_w   = (const float*)d_in[20];
    const float* fc_b   = (const float*)d_in[21];
    float* out = (float*)d_out;

    const int E1 = in_sizes[2] / 2;
    const int E2 = in_sizes[5] / 2;
    const int E3 = in_sizes[8] / 2;

    // workspace layout
    float* ws  = (float*)d_ws;
    float* p0  = ws;                      // N1
    float* h1  = p0 + N1;                 // N1*32
    float* p1  = h1 + (size_t)N1 * 32;    // N2*32
    float* h2  = p1 + (size_t)N2 * 32;    // N2*32
    float* p2  = h2 + (size_t)N2 * 32;    // N3*32
    float* h3  = p2 + (size_t)N3 * 32;    // N3*32
    float* p3  = h3 + (size_t)N3 * 32;    // B8*32
    int*   cnt = (int*)(p3 + (size_t)B8 * 32);  // N1 (hist, then cursor)
    int*   row_start = cnt + N1;          // N1+1
    int*   csr = row_start + N1 + 1;      // E1 (max)
    unsigned* enc = (unsigned*)(csr + E1); // max N2*32 = 1M

    const int T = 256;

    // ---- level 0 pool: x [N0,1] -> p0 [N1] ----
    hipMemsetAsync(enc, 0, (size_t)N1 * 4, stream);
    pool_enc_kernel<<<cdiv(N0, T), T, 0, stream>>>(x, cl0, enc, N0, 1);
    decode_kernel<<<cdiv(N1, T), T, 0, stream>>>(enc, p0, N1);

    // ---- conv1: p0 -> h1 [N1,32] ----
    hipMemsetAsync(cnt, 0, (size_t)N1 * 4, stream);
    hist_kernel<<<cdiv(E1, T), T, 0, stream>>>(ei1, cnt, E1);
    scan_kernel<<<1, 1024, 0, stream>>>(cnt, row_start, N1);
    hipMemsetAsync(cnt, 0, (size_t)N1 * 4, stream);
    scatter_kernel<<<cdiv(E1, T), T, 0, stream>>>(ei1, cnt, row_start, csr, E1);
    conv1_node_kernel<<<cdiv((long long)N1 * 32, T), T, 0, stream>>>(
        p0, ei1, ps1, row_start, csr, W1, root1, b1, h1, N1);

    // ---- pool1: h1 [N1,32] -> p1 [N2,32] ----
    hipMemsetAsync(enc, 0, (size_t)N2 * 32 * 4, stream);
    pool_enc_kernel<<<cdiv((long long)N1 * 32, T), T, 0, stream>>>(h1, cl1, enc, N1, 32);
    decode_kernel<<<cdiv((long long)N2 * 32, T), T, 0, stream>>>(enc, p1, N2 * 32);

    // ---- conv2: p1 -> h2 [N2,32] ----
    hipMemsetAsync(cnt, 0, (size_t)N2 * 4, stream);
    hist_kernel<<<cdiv(E2, T), T, 0, stream>>>(ei2, cnt, E2);
    scan_kernel<<<1, 1024, 0, stream>>>(cnt, row_start, N2);
    hipMemsetAsync(cnt, 0, (size_t)N2 * 4, stream);
    scatter_kernel<<<cdiv(E2, T), T, 0, stream>>>(ei2, cnt, row_start, csr, E2);
    conv32_node_kernel<<<cdiv((long long)N2 * 32, T), T, 0, stream>>>(
        p1, ei2, ps2, row_start, csr, W2, root2, b2, h2, N2);

    // ---- pool2: h2 [N2,32] -> p2 [N3,32] ----
    hipMemsetAsync(enc, 0, (size_t)N3 * 32 * 4, stream);
    pool_enc_kernel<<<cdiv((long long)N2 * 32, T), T, 0, stream>>>(h2, cl2, enc, N2, 32);
    decode_kernel<<<cdiv((long long)N3 * 32, T), T, 0, stream>>>(enc, p2, N3 * 32);

    // ---- conv3: p2 -> h3 [N3,32] ----
    hipMemsetAsync(cnt, 0, (size_t)N3 * 4, stream);
    hist_kernel<<<cdiv(E3, T), T, 0, stream>>>(ei3, cnt, E3);
    scan_kernel<<<1, 1024, 0, stream>>>(cnt, row_start, N3);
    hipMemsetAsync(cnt, 0, (size_t)N3 * 4, stream);
    scatter_kernel<<<cdiv(E3, T), T, 0, stream>>>(ei3, cnt, row_start, csr, E3);
    conv32_node_kernel<<<cdiv((long long)N3 * 32, T), T, 0, stream>>>(
        p2, ei3, ps3, row_start, csr, W3, root3, b3, h3, N3);

    // ---- pool3: h3 [N3,32] -> p3 [B8,32] ----
    hipMemsetAsync(enc, 0, (size_t)B8 * 32 * 4, stream);
    pool_enc_kernel<<<cdiv((long long)N3 * 32, T), T, 0, stream>>>(h3, cl3, enc, N3, 32);
    decode_kernel<<<cdiv((long long)B8 * 32, T), T, 0, stream>>>(enc, p3, B8 * 32);

    // ---- FC + log_softmax: p3 viewed as [B,256] -> out [B,10] ----
    fc_kernel<<<cdiv(B, T), T, 0, stream>>>(p3, fc_w, fc_b, out, B);
}